// Round 10
// baseline (274.327 us; speedup 1.0000x reference)
//
#include <hip/hip_runtime.h>

// VQ argmin: 1-pass f16 SCREEN on matrix cores (xh.ch only, score error
// sigma ~9e-3) + exact fp32 parallel rescan for tokens whose screen
// best2-best1 gap < MARGIN (expected ~1.5% of tokens).
// R9: K-SPLIT x2 on the verbatim R0/R8 staged structure (R6 proved K-split
// raises occupancy to 45%; its failure was the launch_bounds VGPR clamp,
// not the split). No clamp here (256,2). As/Bs LDS aliased (A tile dead
// after ahi preload; K-loop's leading barrier orders preload before DMA
// overwrite) -> 32 KB LDS -> blocks/CU = min(LDS 5, VGPR 4, grid 4) = 4,
// 16 waves/CU (2x R8). Inner loop/fold/reductions byte-identical to R8.
// Finalize moved to merge kernel (argmin domain: take=b1<b0 so cross-half
// ties keep half0's lower indices; sec_union=min(max(b0,b1),s0,s1)).
// rescan v2 + apply verbatim from R8 (verified).

#define M_TOK  32768
#define DIM    128
#define KCODES 8192
#define BM     64
#define NT     16               // tiles of 256 codes per block (half of K)
#define MARGIN 0.10f            // ~8 sigma of screen pair error; gap scale 6.9
#define RTG    8                // tokens per rescan group

typedef _Float16 half8v __attribute__((ext_vector_type(8)));
typedef float float4v __attribute__((ext_vector_type(4)));

union H2U { _Float16 h; unsigned short u; };
__device__ __forceinline__ unsigned short f2h_bits(_Float16 h) {
  H2U c; c.h = h; return c.u;
}

__device__ __forceinline__ void gload_lds16(const void* g, void* l) {
  __builtin_amdgcn_global_load_lds(
      (const __attribute__((address_space(1))) unsigned int*)g,
      (__attribute__((address_space(3))) unsigned int*)l, 16, 0, 0);
}

// ws layout: Cs | cnorm | qcnt | qtok | kmin | partB | partS | partI
#define CNORM_OFF  (KCODES * 256)
#define QCNT_OFF   (CNORM_OFF + KCODES * 4)
#define QTOK_OFF   (QCNT_OFF + 64)
#define KMIN_OFF   (QTOK_OFF + M_TOK * 4)
#define PARTB_OFF  (KMIN_OFF + M_TOK * 8)
#define PARTS_OFF  (PARTB_OFF + M_TOK * 8)   // 2 halves x 4B
#define PARTI_OFF  (PARTS_OFF + M_TOK * 8)

// -------------------------------------------------------------------------
// prep: exact fp32 cnorm + f16-hi codebook rows. Zeroes qcnt.
__global__ __launch_bounds__(256) void prep_kernel(
    const float* __restrict__ cb, unsigned short* __restrict__ Cs,
    float* __restrict__ cnorm, int* __restrict__ qcnt) {
  if (blockIdx.x == 0 && threadIdx.x == 0) *qcnt = 0;
  const int k = blockIdx.x * 4 + (threadIdx.x >> 6);
  const int lane = threadIdx.x & 63;
  const float2 v = ((const float2*)(cb + (size_t)k * DIM))[lane];
  float s = v.x * v.x + v.y * v.y;
  #pragma unroll
  for (int off = 32; off > 0; off >>= 1) s += __shfl_down(s, off);
  if (lane == 0) cnorm[k] = s;
  ushort2 hi;
  hi.x = f2h_bits((_Float16)v.x);
  hi.y = f2h_bits((_Float16)v.y);
  *(ushort2*)(Cs + (size_t)k * 128 + lane * 2) = hi;
}

// -------------------------------------------------------------------------
// Screen: block bid = token group (bid>>1)*64, code half (bid&1)*4096.
__global__ __launch_bounds__(256, 2) void vq_mfma_kernel(
    const float* __restrict__ ze, const unsigned short* __restrict__ Cs,
    const float* __restrict__ cnorm,
    float* __restrict__ partB, float* __restrict__ partS,
    float* __restrict__ partI) {
  // Phase 1: As = lds[0:16K) (64 rows x 256 B, seg-XOR swizzled).
  // Phase 2: B staging ALIASES the same 32 KB (4 waves x 8 KB, 2 slice
  // bufs each). A tile is dead after the ahi register preload; the K-loop's
  // leading __syncthreads orders all preloads before any DMA overwrite.
  __shared__ char lds[32768];
  char* const As = lds;

  const int tid = threadIdx.x;
  const int wn = tid >> 6;
  const int lane = tid & 63;
  const int quad = lane >> 4;
  const int l15 = lane & 15;
  const int m0 = (blockIdx.x >> 1) * BM;
  const int kh = blockIdx.x & 1;
  const int cbase = kh * 4096;

  // Per-lane B-staging source offsets (verified mapping, hi-only rows:
  // 256 B stride). Dest slot s of local row r holds source seg s^((r>>1)&3).
  int loffC[4];
  #pragma unroll
  for (int c = 0; c < 4; ++c) {
    const int r = c * 16 + (lane >> 2);
    const int s = lane & 3;
    const int seg = s ^ ((r >> 1) & 3);
    loffC[c] = (wn * 64 + r) * 256 + seg * 16;
  }
  int boff[4];
  #pragma unroll
  for (int j = 0; j < 4; ++j) {
    const int n = j * 16 + l15;
    boff[j] = n * 64 + ((quad ^ ((n >> 1) & 3)) << 4);
  }
  char* const BsW = lds + wn * 8192;

  // ---- stage As (hi only): fp32 -> f16, seg = (c>>3) ^ (r&7), 256 B rows --
  {
    const int r = tid >> 2;
    const int qh = tid & 3;
    const float* zrow = ze + (size_t)(m0 + r) * DIM + qh * 32;
    char* arow = As + r * 256;
    const int rx = r & 7;
    #pragma unroll
    for (int i = 0; i < 8; ++i) {
      const float4 v = *(const float4*)(zrow + i * 4);
      ushort4 hh;
      hh.x = f2h_bits((_Float16)v.x);
      hh.y = f2h_bits((_Float16)v.y);
      hh.z = f2h_bits((_Float16)v.z);
      hh.w = f2h_bits((_Float16)v.w);
      const int c = qh * 32 + i * 4;
      *(ushort4*)(arow + ((((c >> 3) ^ rx) << 4) | ((c & 7) << 1))) = hh;
    }
  }
  __syncthreads();

  // Preload all A-hi fragments into registers (reused for all 16 n-tiles).
  half8v ahi[4][4];
  #pragma unroll
  for (int ks = 0; ks < 4; ++ks)
    #pragma unroll
    for (int i = 0; i < 4; ++i) {
      const int m = i * 16 + l15;
      const int kslot = ks * 4 + quad;
      ahi[ks][i] = *(const half8v*)(As + m * 256 + ((kslot ^ (m & 7)) << 4));
    }

  float bestv[16], secv[16], idxv[16];
  #pragma unroll
  for (int s = 0; s < 16; ++s) {
    bestv[s] = 3.4e38f; secv[s] = 3.4e38f; idxv[s] = 0.f;
  }

  for (int nt = 0; nt < NT; ++nt) {
    const char* const tile =
        (const char*)Cs + (size_t)cbase * 256 + (size_t)nt * 65536;
    float cnv[4];
    #pragma unroll
    for (int j = 0; j < 4; ++j)
      cnv[j] = cnorm[cbase + nt * 256 + wn * 64 + j * 16 + l15];

    float4v acc[4][4];
    #pragma unroll
    for (int i = 0; i < 4; ++i)
      #pragma unroll
      for (int j = 0; j < 4; ++j) acc[i][j] = (float4v)0.0f;

    // 4 k-slices per tile, staged TWO per barrier pair (halves drain count).
    #pragma unroll
    for (int t = 0; t < 2; ++t) {
      __syncthreads();  // prior pair (or ahi preload) done before overwrite
      #pragma unroll
      for (int p = 0; p < 2; ++p)
        #pragma unroll
        for (int c = 0; c < 4; ++c)
          gload_lds16(tile + (t * 2 + p) * 64 + loffC[c],
                      BsW + p * 4096 + c * 1024);
      __syncthreads();  // drains vmcnt -> both slices ready

      #pragma unroll
      for (int p = 0; p < 2; ++p) {
        const int kk = t * 2 + p;
        half8v bf[4];
        #pragma unroll
        for (int j = 0; j < 4; ++j)
          bf[j] = *(const half8v*)(BsW + p * 4096 + boff[j]);
        #pragma unroll
        for (int i = 0; i < 4; ++i)
          #pragma unroll
          for (int j = 0; j < 4; ++j)
            acc[i][j] = __builtin_amdgcn_mfma_f32_16x16x32_f16(
                ahi[kk][i], bf[j], acc[i][j], 0, 0, 0);
      }
    }

    // Fold screen scores. Ascending n, strict < -> lowest index on ties.
    #pragma unroll
    for (int j = 0; j < 4; ++j) {
      const float nidx = (float)(cbase + nt * 256 + wn * 64 + j * 16 + l15);
      const float cn = cnv[j];
      #pragma unroll
      for (int i = 0; i < 4; ++i)
        #pragma unroll
        for (int rg = 0; rg < 4; ++rg) {
          const float sc = fmaf(-2.0f, acc[i][j][rg], cn);
          const int slot = i * 4 + rg;
          const bool bt = sc < bestv[slot];
          secv[slot] = bt ? bestv[slot] : fminf(secv[slot], sc);
          idxv[slot] = bt ? nidx : idxv[slot];
          bestv[slot] = bt ? sc : bestv[slot];
        }
    }
  }

  // Cross-lane reduce (16 lanes per token row, tie -> lowest index).
  #pragma unroll
  for (int slot = 0; slot < 16; ++slot) {
    float b = bestv[slot], sec = secv[slot], ix = idxv[slot];
    #pragma unroll
    for (int mk = 1; mk <= 8; mk <<= 1) {
      const float ob = __shfl_xor(b, mk);
      const float os = __shfl_xor(sec, mk);
      const float oi = __shfl_xor(ix, mk);
      const bool take = (ob < b) || (ob == b && oi < ix);
      const float loser = take ? b : ob;
      b = take ? ob : b;
      ix = take ? oi : ix;
      sec = fminf(fminf(sec, os), loser);
    }
    bestv[slot] = b; secv[slot] = sec; idxv[slot] = ix;
  }

  // Cross-wave merge via LDS (reuse lds after barrier; all DMA retired).
  __syncthreads();
  float* const redB = (float*)lds;
  float* const redS = redB + 256;
  float* const redI = redB + 512;
  if (l15 == 0) {
    #pragma unroll
    for (int slot = 0; slot < 16; ++slot) {
      const int row = (slot >> 2) * 16 + quad * 4 + (slot & 3);
      redB[wn * 64 + row] = bestv[slot];
      redS[wn * 64 + row] = secv[slot];
      redI[wn * 64 + row] = idxv[slot];
    }
  }
  __syncthreads();
  if (tid < 64) {
    float b = redB[tid], sec = redS[tid], ix = redI[tid];
    #pragma unroll
    for (int w = 1; w < 4; ++w) {
      const float ob = redB[w * 64 + tid];
      const float os = redS[w * 64 + tid];
      const float oi = redI[w * 64 + tid];
      const bool take = (ob < b) || (ob == b && oi < ix);
      const float loser = take ? b : ob;
      b = take ? ob : b;
      ix = take ? oi : ix;
      sec = fminf(fminf(sec, os), loser);
    }
    const int token = m0 + tid;
    partB[token * 2 + kh] = b;
    partS[token * 2 + kh] = sec;
    partI[token * 2 + kh] = ix;
  }
}

// -------------------------------------------------------------------------
// Merge halves (argmin domain), gap test, provisional z_q gather.
// 32 tokens per block. Cross-half tie keeps half 0 (always lower indices).
__global__ __launch_bounds__(256) void merge_gather_kernel(
    const float* __restrict__ cb,
    const float* __restrict__ partB, const float* __restrict__ partS,
    const float* __restrict__ partI,
    int* __restrict__ qcnt, int* __restrict__ qtok,
    unsigned long long* __restrict__ kmin,
    float* __restrict__ out_zq, float* __restrict__ out_idx) {
  __shared__ float lidx[32];
  const int tid = threadIdx.x;
  const int t0 = blockIdx.x * 32;
  if (tid < 32) {
    const int token = t0 + tid;
    const float b0 = partB[token * 2 + 0], b1 = partB[token * 2 + 1];
    const float s0 = partS[token * 2 + 0], s1 = partS[token * 2 + 1];
    const float i0 = partI[token * 2 + 0], i1 = partI[token * 2 + 1];
    const bool take = b1 < b0;           // strict: tie -> half 0
    const float b = take ? b1 : b0;
    const float ix = take ? i1 : i0;
    // Runner-up of union: loser's best vs both halves' seconds.
    const float sec = fminf(fmaxf(b0, b1), fminf(s0, s1));
    out_idx[token] = ix;
    lidx[tid] = ix;
    if (sec - b < MARGIN) {  // ambiguous under screen error -> exact rescan
      kmin[token] = ~0ull;
      const int p = atomicAdd(qcnt, 1);
      qtok[p] = token;
    }
  }
  __syncthreads();
  // z_q gather: 8 threads per token, 4 float4 each.
  const int tl = tid >> 3, qp = tid & 7;
  const int code = (int)lidx[tl];
  const float4* src = (const float4*)(cb + (size_t)code * DIM);
  float4* dst = (float4*)(out_zq + (size_t)(t0 + tl) * DIM);
  #pragma unroll
  for (int p = 0; p < 4; ++p) dst[qp + p * 8] = src[qp + p * 8];
}

// -------------------------------------------------------------------------
// Parallel exact rescan v2 (verified R8). Block b: code-group (b&7)*1024,
// token group (b>>3): RTG tokens staged in LDS, 4 codes/thread.
__global__ __launch_bounds__(256) void rescan_part_kernel(
    const float* __restrict__ ze, const float* __restrict__ cb,
    const float* __restrict__ cnorm, const int* __restrict__ qcnt,
    const int* __restrict__ qtok, unsigned long long* __restrict__ kmin) {
  __shared__ float xsh[RTG][132];                 // padded: bank-spread
  __shared__ unsigned long long wpart[4][RTG];
  const int tid = threadIdx.x;
  const int wv = tid >> 6;
  const int lane = tid & 63;
  const int cg = blockIdx.x & 7;                  // code group (1024 codes)
  const int n = *qcnt;
  const int nslots = gridDim.x >> 3;
  const int c0 = cg * 1024 + tid;                 // codes c0 + k*256, k=0..3

  for (int g = blockIdx.x >> 3; g * RTG < n; g += nslots) {
    const int cnt = min(RTG, n - g * RTG);
    __syncthreads();                              // xsh/wpart safe to reuse
    if ((tid >> 5) < cnt) {                       // 8 tokens x 32 float4
      const int token = qtok[g * RTG + (tid >> 5)];
      const float4 v =
          ((const float4*)(ze + (size_t)token * DIM))[tid & 31];
      ((float4*)(xsh[tid >> 5]))[tid & 31] = v;
    }
    __syncthreads();

    float dot[4][RTG];
    #pragma unroll
    for (int k = 0; k < 4; ++k)
      #pragma unroll
      for (int t = 0; t < RTG; ++t) dot[k][t] = 0.f;

    const float* crow0 = cb + (size_t)c0 * DIM;
    for (int d = 0; d < DIM; d += 4) {
      float4 x4[RTG];
      #pragma unroll
      for (int t = 0; t < RTG; ++t)
        x4[t] = *(const float4*)(xsh[t] + d);     // wave-uniform broadcast
      #pragma unroll
      for (int k = 0; k < 4; ++k) {
        const float4 c4 = *(const float4*)(crow0 + (size_t)k * 256 * DIM + d);
        #pragma unroll
        for (int t = 0; t < RTG; ++t) {
          dot[k][t] = fmaf(c4.x, x4[t].x, dot[k][t]);
          dot[k][t] = fmaf(c4.y, x4[t].y, dot[k][t]);
          dot[k][t] = fmaf(c4.z, x4[t].z, dot[k][t]);
          dot[k][t] = fmaf(c4.w, x4[t].w, dot[k][t]);
        }
      }
    }

    float cn[4];
    #pragma unroll
    for (int k = 0; k < 4; ++k) cn[k] = cnorm[c0 + k * 256];

    #pragma unroll
    for (int t = 0; t < RTG; ++t) {
      float s = fmaf(-2.f, dot[0][t], cn[0]);
      int ix = c0;
      #pragma unroll
      for (int k = 1; k < 4; ++k) {
        const float sk = fmaf(-2.f, dot[k][t], cn[k]);
        if (sk < s) { s = sk; ix = c0 + k * 256; }
      }
      #pragma unroll
      for (int mk = 1; mk <= 32; mk <<= 1) {
        const float os = __shfl_xor(s, mk);
        const int oi = __shfl_xor(ix, mk);
        if (os < s || (os == s && oi < ix)) { s = os; ix = oi; }
      }
      if (lane == 0) {
        union { float f; unsigned u; } c; c.f = s;
        const unsigned m = (c.u >> 31) ? ~c.u : (c.u | 0x80000000u);
        wpart[wv][t] = ((unsigned long long)m << 32) | (unsigned)ix;
      }
    }
    __syncthreads();
    if (tid < cnt) {
      unsigned long long k = wpart[0][tid];
      #pragma unroll
      for (int w = 1; w < 4; ++w) k = min(k, wpart[w][tid]);
      atomicMin(&kmin[qtok[g * RTG + tid]], k);
    }
  }
}

// -------------------------------------------------------------------------
// Apply rescan results: decode keys, rewrite idx + z_q rows.
__global__ __launch_bounds__(256) void rescan_apply_kernel(
    const float* __restrict__ cb, const int* __restrict__ qcnt,
    const int* __restrict__ qtok, const unsigned long long* __restrict__ kmin,
    float* __restrict__ out_zq, float* __restrict__ out_idx) {
  const int tid = threadIdx.x;
  const int n = *qcnt;
  for (int qi = blockIdx.x; qi < n; qi += gridDim.x) {
    const int token = qtok[qi];
    const int code = (int)(unsigned int)(kmin[token] & 0xFFFFFFFFull);
    if (tid == 0) out_idx[token] = (float)code;
    if (tid < 32)
      ((float4*)(out_zq + (size_t)token * DIM))[tid] =
          ((const float4*)(cb + (size_t)code * DIM))[tid];
  }
}

// -------------------------------------------------------------------------
extern "C" void kernel_launch(void* const* d_in, const int* in_sizes, int n_in,
                              void* d_out, int out_size, void* d_ws,
                              size_t ws_size, hipStream_t stream) {
  const float* ze = (const float*)d_in[0];
  const float* cb = (const float*)d_in[1];
  float* out = (float*)d_out;

  unsigned short* Cs = (unsigned short*)d_ws;
  float* cnorm = (float*)((char*)d_ws + CNORM_OFF);
  int* qcnt = (int*)((char*)d_ws + QCNT_OFF);
  int* qtok = (int*)((char*)d_ws + QTOK_OFF);
  unsigned long long* kmin = (unsigned long long*)((char*)d_ws + KMIN_OFF);
  float* partB = (float*)((char*)d_ws + PARTB_OFF);
  float* partS = (float*)((char*)d_ws + PARTS_OFF);
  float* partI = (float*)((char*)d_ws + PARTI_OFF);

  prep_kernel<<<KCODES / 4, 256, 0, stream>>>(cb, Cs, cnorm, qcnt);
  vq_mfma_kernel<<<(M_TOK / BM) * 2, 256, 0, stream>>>(
      ze, Cs, cnorm, partB, partS, partI);
  merge_gather_kernel<<<M_TOK / 32, 256, 0, stream>>>(
      cb, partB, partS, partI, qcnt, qtok, kmin, out,
      out + (size_t)M_TOK * DIM);
  rescan_part_kernel<<<4096, 256, 0, stream>>>(ze, cb, cnorm, qcnt, qtok,
                                               kmin);
  rescan_apply_kernel<<<256, 256, 0, stream>>>(cb, qcnt, qtok, kmin, out,
                                               out + (size_t)M_TOK * DIM);
}

// Round 11
// 271.910 us; speedup vs baseline: 1.0089x; 1.0089x over previous
//
#include <hip/hip_runtime.h>

// VQ argmin: 1-pass f16 SCREEN on matrix cores (xh.ch only, score error
// sigma ~9e-3) + exact fp32 parallel rescan for tokens whose screen
// best2-best1 gap < MARGIN (expected ~1.5% of tokens).
// R10: R8 verbatim (best verified: 255.9us; vq ~120us is this structure's
// floor -- R1-R9 showed occupancy/restructure levers are dead on it). The
// win target is DISPATCH COUNT: ~90us of wall time is inter-kernel gaps
// (kernel-time sum ~165us vs 256us wall). rescan_apply is FUSED into
// rescan_part via per-token done-counters: each of the 8 code-group blocks
// atomicMin's its partial, __threadfence(), atomicAdd(done); the block
// seeing old==7 re-reads the final key with a no-op atomicMin (coherent
// RMW) and writes idx + z_q itself. vq zeroes done[] alongside kmin init
// (re-poison safe). 4 kernels -> 3.

#define M_TOK  32768
#define DIM    128
#define KCODES 8192
#define BM     64
#define NT     (KCODES / 256)   // 32 n-tiles per block
#define MARGIN 0.10f            // ~8 sigma of screen pair error; gap scale 6.9
#define RTG    8                // tokens per rescan group

typedef _Float16 half8v __attribute__((ext_vector_type(8)));
typedef float float4v __attribute__((ext_vector_type(4)));

union H2U { _Float16 h; unsigned short u; };
__device__ __forceinline__ unsigned short f2h_bits(_Float16 h) {
  H2U c; c.h = h; return c.u;
}

__device__ __forceinline__ void gload_lds16(const void* g, void* l) {
  __builtin_amdgcn_global_load_lds(
      (const __attribute__((address_space(1))) unsigned int*)g,
      (__attribute__((address_space(3))) unsigned int*)l, 16, 0, 0);
}

// ws layout: Cs f16[K][128] | cnorm f32[K] | qcnt | qtok | kmin | done
#define CNORM_OFF  (KCODES * 256)
#define QCNT_OFF   (CNORM_OFF + KCODES * 4)
#define QTOK_OFF   (QCNT_OFF + 64)
#define KMIN_OFF   (QTOK_OFF + M_TOK * 4)
#define DONE_OFF   (KMIN_OFF + M_TOK * 8)

// -------------------------------------------------------------------------
// prep: exact fp32 cnorm + f16-hi codebook rows. Zeroes qcnt.
__global__ __launch_bounds__(256) void prep_kernel(
    const float* __restrict__ cb, unsigned short* __restrict__ Cs,
    float* __restrict__ cnorm, int* __restrict__ qcnt) {
  if (blockIdx.x == 0 && threadIdx.x == 0) *qcnt = 0;
  const int k = blockIdx.x * 4 + (threadIdx.x >> 6);
  const int lane = threadIdx.x & 63;
  const float2 v = ((const float2*)(cb + (size_t)k * DIM))[lane];
  float s = v.x * v.x + v.y * v.y;
  #pragma unroll
  for (int off = 32; off > 0; off >>= 1) s += __shfl_down(s, off);
  if (lane == 0) cnorm[k] = s;
  ushort2 hi;
  hi.x = f2h_bits((_Float16)v.x);
  hi.y = f2h_bits((_Float16)v.y);
  *(ushort2*)(Cs + (size_t)k * 128 + lane * 2) = hi;
}

// -------------------------------------------------------------------------
__global__ __launch_bounds__(256, 2) void vq_mfma_kernel(
    const float* __restrict__ ze, const unsigned short* __restrict__ Cs,
    const float* __restrict__ cnorm, const float* __restrict__ cb,
    int* __restrict__ qcnt, int* __restrict__ qtok,
    unsigned long long* __restrict__ kmin, int* __restrict__ done,
    float* __restrict__ out_zq, float* __restrict__ out_idx) {
  __shared__ char lds[49152];
  char* const As = lds;            // 16 KB: 64 rows x 256 B, seg-XOR swizzled
  char* const Bs = lds + 16384;    // 32 KB: 4 waves x 8 KB (2 slice bufs)

  const int tid = threadIdx.x;
  const int wn = tid >> 6;
  const int lane = tid & 63;
  const int quad = lane >> 4;
  const int l15 = lane & 15;
  const int m0 = blockIdx.x * BM;

  // Per-lane B-staging source offsets (verified mapping, hi-only rows:
  // 256 B stride). Dest slot s of local row r holds source seg s^((r>>1)&3).
  int loffC[4];
  #pragma unroll
  for (int c = 0; c < 4; ++c) {
    const int r = c * 16 + (lane >> 2);
    const int s = lane & 3;
    const int seg = s ^ ((r >> 1) & 3);
    loffC[c] = (wn * 64 + r) * 256 + seg * 16;
  }
  int boff[4];
  #pragma unroll
  for (int j = 0; j < 4; ++j) {
    const int n = j * 16 + l15;
    boff[j] = n * 64 + ((quad ^ ((n >> 1) & 3)) << 4);
  }
  char* const BsW = Bs + wn * 8192;

  // ---- stage As (hi only): fp32 -> f16, seg = (c>>3) ^ (r&7), 256 B rows --
  {
    const int r = tid >> 2;
    const int qh = tid & 3;
    const float* zrow = ze + (size_t)(m0 + r) * DIM + qh * 32;
    char* arow = As + r * 256;
    const int rx = r & 7;
    #pragma unroll
    for (int i = 0; i < 8; ++i) {
      const float4 v = *(const float4*)(zrow + i * 4);
      ushort4 hh;
      hh.x = f2h_bits((_Float16)v.x);
      hh.y = f2h_bits((_Float16)v.y);
      hh.z = f2h_bits((_Float16)v.z);
      hh.w = f2h_bits((_Float16)v.w);
      const int c = qh * 32 + i * 4;
      *(ushort4*)(arow + ((((c >> 3) ^ rx) << 4) | ((c & 7) << 1))) = hh;
    }
  }
  __syncthreads();

  // Preload all A-hi fragments into registers (reused for all 32 n-tiles).
  half8v ahi[4][4];
  #pragma unroll
  for (int ks = 0; ks < 4; ++ks)
    #pragma unroll
    for (int i = 0; i < 4; ++i) {
      const int m = i * 16 + l15;
      const int kslot = ks * 4 + quad;
      ahi[ks][i] = *(const half8v*)(As + m * 256 + ((kslot ^ (m & 7)) << 4));
    }

  float bestv[16], secv[16], idxv[16];
  #pragma unroll
  for (int s = 0; s < 16; ++s) {
    bestv[s] = 3.4e38f; secv[s] = 3.4e38f; idxv[s] = 0.f;
  }

  for (int nt = 0; nt < NT; ++nt) {
    const char* const tile = (const char*)Cs + (size_t)nt * 65536;
    float cnv[4];
    #pragma unroll
    for (int j = 0; j < 4; ++j)
      cnv[j] = cnorm[nt * 256 + wn * 64 + j * 16 + l15];

    float4v acc[4][4];
    #pragma unroll
    for (int i = 0; i < 4; ++i)
      #pragma unroll
      for (int j = 0; j < 4; ++j) acc[i][j] = (float4v)0.0f;

    // 4 k-slices per tile, staged TWO per barrier pair (halves drain count).
    #pragma unroll
    for (int t = 0; t < 2; ++t) {
      __syncthreads();  // prior pair consumed before DMA overwrite
      #pragma unroll
      for (int p = 0; p < 2; ++p)
        #pragma unroll
        for (int c = 0; c < 4; ++c)
          gload_lds16(tile + (t * 2 + p) * 64 + loffC[c],
                      BsW + p * 4096 + c * 1024);
      __syncthreads();  // drains vmcnt -> both slices ready

      #pragma unroll
      for (int p = 0; p < 2; ++p) {
        const int kk = t * 2 + p;
        half8v bf[4];
        #pragma unroll
        for (int j = 0; j < 4; ++j)
          bf[j] = *(const half8v*)(BsW + p * 4096 + boff[j]);
        #pragma unroll
        for (int i = 0; i < 4; ++i)
          #pragma unroll
          for (int j = 0; j < 4; ++j)
            acc[i][j] = __builtin_amdgcn_mfma_f32_16x16x32_f16(
                ahi[kk][i], bf[j], acc[i][j], 0, 0, 0);
      }
    }

    // Fold screen scores. Ascending n, strict < -> lowest index on ties.
    #pragma unroll
    for (int j = 0; j < 4; ++j) {
      const float nidx = (float)(nt * 256 + wn * 64 + j * 16 + l15);
      const float cn = cnv[j];
      #pragma unroll
      for (int i = 0; i < 4; ++i)
        #pragma unroll
        for (int rg = 0; rg < 4; ++rg) {
          const float sc = fmaf(-2.0f, acc[i][j][rg], cn);
          const int slot = i * 4 + rg;
          const bool bt = sc < bestv[slot];
          secv[slot] = bt ? bestv[slot] : fminf(secv[slot], sc);
          idxv[slot] = bt ? nidx : idxv[slot];
          bestv[slot] = bt ? sc : bestv[slot];
        }
    }
  }

  // Cross-lane reduce (16 lanes per token row, tie -> lowest index).
  #pragma unroll
  for (int slot = 0; slot < 16; ++slot) {
    float b = bestv[slot], sec = secv[slot], ix = idxv[slot];
    #pragma unroll
    for (int mk = 1; mk <= 8; mk <<= 1) {
      const float ob = __shfl_xor(b, mk);
      const float os = __shfl_xor(sec, mk);
      const float oi = __shfl_xor(ix, mk);
      const bool take = (ob < b) || (ob == b && oi < ix);
      const float loser = take ? b : ob;
      b = take ? ob : b;
      ix = take ? oi : ix;
      sec = fminf(fminf(sec, os), loser);
    }
    bestv[slot] = b; secv[slot] = sec; idxv[slot] = ix;
  }

  // Cross-wave merge via LDS (reuse As region after barrier).
  __syncthreads();
  float* const redB = (float*)lds;
  float* const redS = redB + 256;
  float* const redI = redB + 512;
  float* const lidxs = redB + 768;
  if (l15 == 0) {
    #pragma unroll
    for (int slot = 0; slot < 16; ++slot) {
      const int row = (slot >> 2) * 16 + quad * 4 + (slot & 3);
      redB[wn * 64 + row] = bestv[slot];
      redS[wn * 64 + row] = secv[slot];
      redI[wn * 64 + row] = idxv[slot];
    }
  }
  __syncthreads();
  if (tid < 64) {
    float b = redB[tid], sec = redS[tid], ix = redI[tid];
    #pragma unroll
    for (int w = 1; w < 4; ++w) {
      const float ob = redB[w * 64 + tid];
      const float os = redS[w * 64 + tid];
      const float oi = redI[w * 64 + tid];
      const bool take = (ob < b) || (ob == b && oi < ix);
      const float loser = take ? b : ob;
      b = take ? ob : b;
      ix = take ? oi : ix;
      sec = fminf(fminf(sec, os), loser);
    }
    out_idx[m0 + tid] = ix;
    lidxs[tid] = ix;
    if (sec - b < MARGIN) {  // ambiguous under screen error -> exact rescan
      kmin[m0 + tid] = ~0ull;
      done[m0 + tid] = 0;
      const int p = atomicAdd(qcnt, 1);
      qtok[p] = m0 + tid;
    }
  }
  __syncthreads();

  // Provisional z_q gather for this block's 64 tokens.
  const int tl = tid >> 2, qp = tid & 3;
  const int code = (int)lidxs[tl];
  const float4* src = (const float4*)(cb + (size_t)code * DIM);
  float4* dst = (float4*)(out_zq + (size_t)(m0 + tl) * DIM);
  #pragma unroll
  for (int p = 0; p < 8; ++p) dst[qp + p * 4] = src[qp + p * 4];
}

// -------------------------------------------------------------------------
// Parallel exact rescan (R8-verified math) with FUSED apply: block b handles
// code-group (b&7)*1024, token group (b>>3) of RTG tokens staged in LDS,
// 4 codes/thread. After atomicMin of this group's partial: threadfence +
// done-counter; the 8th arriving block re-reads the final key (no-op
// atomicMin = coherent RMW read), decodes, writes idx + exact z_q row.
__global__ __launch_bounds__(256) void rescan_part_kernel(
    const float* __restrict__ ze, const float* __restrict__ cb,
    const float* __restrict__ cnorm, const int* __restrict__ qcnt,
    const int* __restrict__ qtok, unsigned long long* __restrict__ kmin,
    int* __restrict__ done,
    float* __restrict__ out_zq, float* __restrict__ out_idx) {
  __shared__ float xsh[RTG][132];                 // padded: bank-spread
  __shared__ unsigned long long wpart[4][RTG];
  const int tid = threadIdx.x;
  const int wv = tid >> 6;
  const int lane = tid & 63;
  const int cg = blockIdx.x & 7;                  // code group (1024 codes)
  const int n = *qcnt;
  const int nslots = gridDim.x >> 3;
  const int c0 = cg * 1024 + tid;                 // codes c0 + k*256, k=0..3

  for (int g = blockIdx.x >> 3; g * RTG < n; g += nslots) {
    const int cnt = min(RTG, n - g * RTG);
    __syncthreads();                              // xsh/wpart safe to reuse
    if ((tid >> 5) < cnt) {                       // 8 tokens x 32 float4
      const int token = qtok[g * RTG + (tid >> 5)];
      const float4 v =
          ((const float4*)(ze + (size_t)token * DIM))[tid & 31];
      ((float4*)(xsh[tid >> 5]))[tid & 31] = v;
    }
    __syncthreads();

    float dot[4][RTG];
    #pragma unroll
    for (int k = 0; k < 4; ++k)
      #pragma unroll
      for (int t = 0; t < RTG; ++t) dot[k][t] = 0.f;

    const float* crow0 = cb + (size_t)c0 * DIM;
    for (int d = 0; d < DIM; d += 4) {
      float4 x4[RTG];
      #pragma unroll
      for (int t = 0; t < RTG; ++t)
        x4[t] = *(const float4*)(xsh[t] + d);     // wave-uniform broadcast
      #pragma unroll
      for (int k = 0; k < 4; ++k) {
        const float4 c4 = *(const float4*)(crow0 + (size_t)k * 256 * DIM + d);
        #pragma unroll
        for (int t = 0; t < RTG; ++t) {
          dot[k][t] = fmaf(c4.x, x4[t].x, dot[k][t]);
          dot[k][t] = fmaf(c4.y, x4[t].y, dot[k][t]);
          dot[k][t] = fmaf(c4.z, x4[t].z, dot[k][t]);
          dot[k][t] = fmaf(c4.w, x4[t].w, dot[k][t]);
        }
      }
    }

    float cn[4];
    #pragma unroll
    for (int k = 0; k < 4; ++k) cn[k] = cnorm[c0 + k * 256];

    #pragma unroll
    for (int t = 0; t < RTG; ++t) {
      float s = fmaf(-2.f, dot[0][t], cn[0]);
      int ix = c0;
      #pragma unroll
      for (int k = 1; k < 4; ++k) {
        const float sk = fmaf(-2.f, dot[k][t], cn[k]);
        if (sk < s) { s = sk; ix = c0 + k * 256; }
      }
      #pragma unroll
      for (int mk = 1; mk <= 32; mk <<= 1) {
        const float os = __shfl_xor(s, mk);
        const int oi = __shfl_xor(ix, mk);
        if (os < s || (os == s && oi < ix)) { s = os; ix = oi; }
      }
      if (lane == 0) {
        union { float f; unsigned u; } c; c.f = s;
        const unsigned m = (c.u >> 31) ? ~c.u : (c.u | 0x80000000u);
        wpart[wv][t] = ((unsigned long long)m << 32) | (unsigned)ix;
      }
    }
    __syncthreads();
    if (tid < cnt) {
      const int token = qtok[g * RTG + tid];
      unsigned long long k = wpart[0][tid];
      #pragma unroll
      for (int w = 1; w < 4; ++w) k = min(k, wpart[w][tid]);
      atomicMin(&kmin[token], k);
      __threadfence();                            // publish min before count
      const int old = atomicAdd(&done[token], 1);
      if (old == 7) {                             // all 8 groups merged
        const unsigned long long fin = atomicMin(&kmin[token], ~0ull);
        const int code = (int)(unsigned int)(fin & 0xFFFFFFFFull);
        out_idx[token] = (float)code;
        const float4* src = (const float4*)(cb + (size_t)code * DIM);
        float4* dst = (float4*)(out_zq + (size_t)token * DIM);
        #pragma unroll
        for (int p = 0; p < 32; ++p) dst[p] = src[p];
      }
    }
    __syncthreads();
  }
}

// -------------------------------------------------------------------------
extern "C" void kernel_launch(void* const* d_in, const int* in_sizes, int n_in,
                              void* d_out, int out_size, void* d_ws,
                              size_t ws_size, hipStream_t stream) {
  const float* ze = (const float*)d_in[0];
  const float* cb = (const float*)d_in[1];
  float* out = (float*)d_out;

  unsigned short* Cs = (unsigned short*)d_ws;
  float* cnorm = (float*)((char*)d_ws + CNORM_OFF);
  int* qcnt = (int*)((char*)d_ws + QCNT_OFF);
  int* qtok = (int*)((char*)d_ws + QTOK_OFF);
  unsigned long long* kmin = (unsigned long long*)((char*)d_ws + KMIN_OFF);
  int* done = (int*)((char*)d_ws + DONE_OFF);

  prep_kernel<<<KCODES / 4, 256, 0, stream>>>(cb, Cs, cnorm, qcnt);
  vq_mfma_kernel<<<M_TOK / BM, 256, 0, stream>>>(
      ze, Cs, cnorm, cb, qcnt, qtok, kmin, done, out,
      out + (size_t)M_TOK * DIM);
  rescan_part_kernel<<<4096, 256, 0, stream>>>(
      ze, cb, cnorm, qcnt, qtok, kmin, done, out, out + (size_t)M_TOK * DIM);
}

// Round 12
// 249.846 us; speedup vs baseline: 1.0980x; 1.0883x over previous
//
#include <hip/hip_runtime.h>

// VQ argmin: 1-pass f16 SCREEN on matrix cores (xh.ch only, score error
// sigma ~9e-3) + exact fp32 parallel rescan for tokens whose screen
// best2-best1 gap < MARGIN (expected ~1.5% of tokens).
// R11: R8 layout verbatim (best verified total, 255.9us; R10's fused-apply
// reverted -- run variance +-10us swamped it, vq counters identical).
// Single change: the fold is R4's verified argmax form (zero-init acc,
// sc = fmaf(-0.5,cn,acc), med3 runner-up, fmaxf best) -- 5 VALU ops per
// candidate vs 6, and cnorm stays OFF the MFMA critical path (R2's mistake
// was bias-init). Cross-lane/cross-wave reduces + gap test in argmax
// domain exactly as R4's passing run (d2-gap = 2*(b-sec) < MARGIN).

#define M_TOK  32768
#define DIM    128
#define KCODES 8192
#define BM     64
#define NT     (KCODES / 256)   // 32 n-tiles per block
#define MARGIN 0.10f            // ~8 sigma of screen pair error; gap scale 6.9
#define RTG    8                // tokens per rescan group

typedef _Float16 half8v __attribute__((ext_vector_type(8)));
typedef float float4v __attribute__((ext_vector_type(4)));

union H2U { _Float16 h; unsigned short u; };
__device__ __forceinline__ unsigned short f2h_bits(_Float16 h) {
  H2U c; c.h = h; return c.u;
}

__device__ __forceinline__ void gload_lds16(const void* g, void* l) {
  __builtin_amdgcn_global_load_lds(
      (const __attribute__((address_space(1))) unsigned int*)g,
      (__attribute__((address_space(3))) unsigned int*)l, 16, 0, 0);
}

// ws layout: Cs f16[K][128] (hi only) | cnorm f32[K] | qcnt | qtok | kmin
#define CNORM_OFF  (KCODES * 256)
#define QCNT_OFF   (CNORM_OFF + KCODES * 4)
#define QTOK_OFF   (QCNT_OFF + 64)
#define KMIN_OFF   (QTOK_OFF + M_TOK * 4)

// -------------------------------------------------------------------------
// prep: exact fp32 cnorm + f16-hi codebook rows. Zeroes qcnt.
__global__ __launch_bounds__(256) void prep_kernel(
    const float* __restrict__ cb, unsigned short* __restrict__ Cs,
    float* __restrict__ cnorm, int* __restrict__ qcnt) {
  if (blockIdx.x == 0 && threadIdx.x == 0) *qcnt = 0;
  const int k = blockIdx.x * 4 + (threadIdx.x >> 6);
  const int lane = threadIdx.x & 63;
  const float2 v = ((const float2*)(cb + (size_t)k * DIM))[lane];
  float s = v.x * v.x + v.y * v.y;
  #pragma unroll
  for (int off = 32; off > 0; off >>= 1) s += __shfl_down(s, off);
  if (lane == 0) cnorm[k] = s;
  ushort2 hi;
  hi.x = f2h_bits((_Float16)v.x);
  hi.y = f2h_bits((_Float16)v.y);
  *(ushort2*)(Cs + (size_t)k * 128 + lane * 2) = hi;
}

// -------------------------------------------------------------------------
__global__ __launch_bounds__(256, 2) void vq_mfma_kernel(
    const float* __restrict__ ze, const unsigned short* __restrict__ Cs,
    const float* __restrict__ cnorm, const float* __restrict__ cb,
    int* __restrict__ qcnt, int* __restrict__ qtok,
    unsigned long long* __restrict__ kmin,
    float* __restrict__ out_zq, float* __restrict__ out_idx) {
  __shared__ char lds[49152];
  char* const As = lds;            // 16 KB: 64 rows x 256 B, seg-XOR swizzled
  char* const Bs = lds + 16384;    // 32 KB: 4 waves x 8 KB (2 slice bufs)

  const int tid = threadIdx.x;
  const int wn = tid >> 6;
  const int lane = tid & 63;
  const int quad = lane >> 4;
  const int l15 = lane & 15;
  const int m0 = blockIdx.x * BM;

  // Per-lane B-staging source offsets (verified mapping, hi-only rows:
  // 256 B stride). Dest slot s of local row r holds source seg s^((r>>1)&3).
  int loffC[4];
  #pragma unroll
  for (int c = 0; c < 4; ++c) {
    const int r = c * 16 + (lane >> 2);
    const int s = lane & 3;
    const int seg = s ^ ((r >> 1) & 3);
    loffC[c] = (wn * 64 + r) * 256 + seg * 16;
  }
  int boff[4];
  #pragma unroll
  for (int j = 0; j < 4; ++j) {
    const int n = j * 16 + l15;
    boff[j] = n * 64 + ((quad ^ ((n >> 1) & 3)) << 4);
  }
  char* const BsW = Bs + wn * 8192;

  // ---- stage As (hi only): fp32 -> f16, seg = (c>>3) ^ (r&7), 256 B rows --
  {
    const int r = tid >> 2;
    const int qh = tid & 3;
    const float* zrow = ze + (size_t)(m0 + r) * DIM + qh * 32;
    char* arow = As + r * 256;
    const int rx = r & 7;
    #pragma unroll
    for (int i = 0; i < 8; ++i) {
      const float4 v = *(const float4*)(zrow + i * 4);
      ushort4 hh;
      hh.x = f2h_bits((_Float16)v.x);
      hh.y = f2h_bits((_Float16)v.y);
      hh.z = f2h_bits((_Float16)v.z);
      hh.w = f2h_bits((_Float16)v.w);
      const int c = qh * 32 + i * 4;
      *(ushort4*)(arow + ((((c >> 3) ^ rx) << 4) | ((c & 7) << 1))) = hh;
    }
  }
  __syncthreads();

  // Preload all A-hi fragments into registers (reused for all 32 n-tiles).
  half8v ahi[4][4];
  #pragma unroll
  for (int ks = 0; ks < 4; ++ks)
    #pragma unroll
    for (int i = 0; i < 4; ++i) {
      const int m = i * 16 + l15;
      const int kslot = ks * 4 + quad;
      ahi[ks][i] = *(const half8v*)(As + m * 256 + ((kslot ^ (m & 7)) << 4));
    }

  // Argmax of sc = x.c - cn/2 (equivalent to argmin of cn - 2 x.c).
  float bestv[16], secv[16], idxv[16];
  #pragma unroll
  for (int s = 0; s < 16; ++s) {
    bestv[s] = -3.4e38f; secv[s] = -3.4e38f; idxv[s] = 0.f;
  }

  for (int nt = 0; nt < NT; ++nt) {
    const char* const tile = (const char*)Cs + (size_t)nt * 65536;
    float cnv[4];
    #pragma unroll
    for (int j = 0; j < 4; ++j)
      cnv[j] = cnorm[nt * 256 + wn * 64 + j * 16 + l15];

    float4v acc[4][4];
    #pragma unroll
    for (int i = 0; i < 4; ++i)
      #pragma unroll
      for (int j = 0; j < 4; ++j) acc[i][j] = (float4v)0.0f;

    // 4 k-slices per tile, staged TWO per barrier pair (halves drain count).
    #pragma unroll
    for (int t = 0; t < 2; ++t) {
      __syncthreads();  // prior pair consumed before DMA overwrite
      #pragma unroll
      for (int p = 0; p < 2; ++p)
        #pragma unroll
        for (int c = 0; c < 4; ++c)
          gload_lds16(tile + (t * 2 + p) * 64 + loffC[c],
                      BsW + p * 4096 + c * 1024);
      __syncthreads();  // drains vmcnt -> both slices ready

      #pragma unroll
      for (int p = 0; p < 2; ++p) {
        const int kk = t * 2 + p;
        half8v bf[4];
        #pragma unroll
        for (int j = 0; j < 4; ++j)
          bf[j] = *(const half8v*)(BsW + p * 4096 + boff[j]);
        #pragma unroll
        for (int i = 0; i < 4; ++i)
          #pragma unroll
          for (int j = 0; j < 4; ++j)
            acc[i][j] = __builtin_amdgcn_mfma_f32_16x16x32_f16(
                ahi[kk][i], bf[j], acc[i][j], 0, 0, 0);
      }
    }

    // Fold screen scores (argmax; R4-verified form). Ascending n, strict >
    // keeps lowest index on ties. sec' = med3(sc, best, sec) is exactly the
    // new runner-up; cnorm folded via fmaf AFTER the MFMA chain.
    #pragma unroll
    for (int j = 0; j < 4; ++j) {
      const float nidx = (float)(nt * 256 + wn * 64 + j * 16 + l15);
      const float cn = cnv[j];
      #pragma unroll
      for (int i = 0; i < 4; ++i)
        #pragma unroll
        for (int rg = 0; rg < 4; ++rg) {
          const float sc = fmaf(-0.5f, cn, acc[i][j][rg]);
          const int slot = i * 4 + rg;
          const bool bt = sc > bestv[slot];
          secv[slot] = __builtin_amdgcn_fmed3f(sc, bestv[slot], secv[slot]);
          idxv[slot] = bt ? nidx : idxv[slot];
          bestv[slot] = fmaxf(bestv[slot], sc);
        }
    }
  }

  // Cross-lane reduce (16 lanes per token row, tie -> lowest index).
  #pragma unroll
  for (int slot = 0; slot < 16; ++slot) {
    float b = bestv[slot], sec = secv[slot], ix = idxv[slot];
    #pragma unroll
    for (int mk = 1; mk <= 8; mk <<= 1) {
      const float ob = __shfl_xor(b, mk);
      const float os = __shfl_xor(sec, mk);
      const float oi = __shfl_xor(ix, mk);
      const bool take = (ob > b) || (ob == b && oi < ix);
      const float loser = take ? b : ob;
      b = take ? ob : b;
      ix = take ? oi : ix;
      sec = fmaxf(fmaxf(sec, os), loser);
    }
    bestv[slot] = b; secv[slot] = sec; idxv[slot] = ix;
  }

  // Cross-wave merge via LDS (reuse As region after barrier).
  __syncthreads();
  float* const redB = (float*)lds;
  float* const redS = redB + 256;
  float* const redI = redB + 512;
  float* const lidxs = redB + 768;
  if (l15 == 0) {
    #pragma unroll
    for (int slot = 0; slot < 16; ++slot) {
      const int row = (slot >> 2) * 16 + quad * 4 + (slot & 3);
      redB[wn * 64 + row] = bestv[slot];
      redS[wn * 64 + row] = secv[slot];
      redI[wn * 64 + row] = idxv[slot];
    }
  }
  __syncthreads();
  if (tid < 64) {
    float b = redB[tid], sec = redS[tid], ix = redI[tid];
    #pragma unroll
    for (int w = 1; w < 4; ++w) {
      const float ob = redB[w * 64 + tid];
      const float os = redS[w * 64 + tid];
      const float oi = redI[w * 64 + tid];
      const bool take = (ob > b) || (ob == b && oi < ix);
      const float loser = take ? b : ob;
      b = take ? ob : b;
      ix = take ? oi : ix;
      sec = fmaxf(fmaxf(sec, os), loser);
    }
    out_idx[m0 + tid] = ix;
    lidxs[tid] = ix;
    // acc-domain gap: d2-gap = 2*(b - sec)  =>  test (b-sec) < MARGIN/2.
    if (b - sec < 0.5f * MARGIN) {  // ambiguous under screen error -> rescan
      kmin[m0 + tid] = ~0ull;
      const int p = atomicAdd(qcnt, 1);
      qtok[p] = m0 + tid;
    }
  }
  __syncthreads();

  // Provisional z_q gather for this block's 64 tokens.
  const int tl = tid >> 2, qp = tid & 3;
  const int code = (int)lidxs[tl];
  const float4* src = (const float4*)(cb + (size_t)code * DIM);
  float4* dst = (float4*)(out_zq + (size_t)(m0 + tl) * DIM);
  #pragma unroll
  for (int p = 0; p < 8; ++p) dst[qp + p * 4] = src[qp + p * 4];
}

// -------------------------------------------------------------------------
// Parallel exact rescan v2 (R8-verified). Block b: code-group (b&7)*1024,
// token group (b>>3): RTG tokens staged in LDS, 4 codes/thread.
__global__ __launch_bounds__(256) void rescan_part_kernel(
    const float* __restrict__ ze, const float* __restrict__ cb,
    const float* __restrict__ cnorm, const int* __restrict__ qcnt,
    const int* __restrict__ qtok, unsigned long long* __restrict__ kmin) {
  __shared__ float xsh[RTG][132];                 // padded: bank-spread
  __shared__ unsigned long long wpart[4][RTG];
  const int tid = threadIdx.x;
  const int wv = tid >> 6;
  const int lane = tid & 63;
  const int cg = blockIdx.x & 7;                  // code group (1024 codes)
  const int n = *qcnt;
  const int nslots = gridDim.x >> 3;
  const int c0 = cg * 1024 + tid;                 // codes c0 + k*256, k=0..3

  for (int g = blockIdx.x >> 3; g * RTG < n; g += nslots) {
    const int cnt = min(RTG, n - g * RTG);
    __syncthreads();                              // xsh/wpart safe to reuse
    if ((tid >> 5) < cnt) {                       // 8 tokens x 32 float4
      const int token = qtok[g * RTG + (tid >> 5)];
      const float4 v =
          ((const float4*)(ze + (size_t)token * DIM))[tid & 31];
      ((float4*)(xsh[tid >> 5]))[tid & 31] = v;
    }
    __syncthreads();

    float dot[4][RTG];
    #pragma unroll
    for (int k = 0; k < 4; ++k)
      #pragma unroll
      for (int t = 0; t < RTG; ++t) dot[k][t] = 0.f;

    const float* crow0 = cb + (size_t)c0 * DIM;
    for (int d = 0; d < DIM; d += 4) {
      float4 x4[RTG];
      #pragma unroll
      for (int t = 0; t < RTG; ++t)
        x4[t] = *(const float4*)(xsh[t] + d);     // wave-uniform broadcast
      #pragma unroll
      for (int k = 0; k < 4; ++k) {
        const float4 c4 = *(const float4*)(crow0 + (size_t)k * 256 * DIM + d);
        #pragma unroll
        for (int t = 0; t < RTG; ++t) {
          dot[k][t] = fmaf(c4.x, x4[t].x, dot[k][t]);
          dot[k][t] = fmaf(c4.y, x4[t].y, dot[k][t]);
          dot[k][t] = fmaf(c4.z, x4[t].z, dot[k][t]);
          dot[k][t] = fmaf(c4.w, x4[t].w, dot[k][t]);
        }
      }
    }

    float cn[4];
    #pragma unroll
    for (int k = 0; k < 4; ++k) cn[k] = cnorm[c0 + k * 256];

    #pragma unroll
    for (int t = 0; t < RTG; ++t) {
      float s = fmaf(-2.f, dot[0][t], cn[0]);
      int ix = c0;
      #pragma unroll
      for (int k = 1; k < 4; ++k) {
        const float sk = fmaf(-2.f, dot[k][t], cn[k]);
        if (sk < s) { s = sk; ix = c0 + k * 256; }
      }
      #pragma unroll
      for (int mk = 1; mk <= 32; mk <<= 1) {
        const float os = __shfl_xor(s, mk);
        const int oi = __shfl_xor(ix, mk);
        if (os < s || (os == s && oi < ix)) { s = os; ix = oi; }
      }
      if (lane == 0) {
        union { float f; unsigned u; } c; c.f = s;
        const unsigned m = (c.u >> 31) ? ~c.u : (c.u | 0x80000000u);
        wpart[wv][t] = ((unsigned long long)m << 32) | (unsigned)ix;
      }
    }
    __syncthreads();
    if (tid < cnt) {
      unsigned long long k = wpart[0][tid];
      #pragma unroll
      for (int w = 1; w < 4; ++w) k = min(k, wpart[w][tid]);
      atomicMin(&kmin[qtok[g * RTG + tid]], k);
    }
  }
}

// -------------------------------------------------------------------------
// Apply rescan results: decode keys, rewrite idx + z_q rows.
__global__ __launch_bounds__(256) void rescan_apply_kernel(
    const float* __restrict__ cb, const int* __restrict__ qcnt,
    const int* __restrict__ qtok, const unsigned long long* __restrict__ kmin,
    float* __restrict__ out_zq, float* __restrict__ out_idx) {
  const int tid = threadIdx.x;
  const int n = *qcnt;
  for (int qi = blockIdx.x; qi < n; qi += gridDim.x) {
    const int token = qtok[qi];
    const int code = (int)(unsigned int)(kmin[token] & 0xFFFFFFFFull);
    if (tid == 0) out_idx[token] = (float)code;
    if (tid < 32)
      ((float4*)(out_zq + (size_t)token * DIM))[tid] =
          ((const float4*)(cb + (size_t)code * DIM))[tid];
  }
}

// -------------------------------------------------------------------------
extern "C" void kernel_launch(void* const* d_in, const int* in_sizes, int n_in,
                              void* d_out, int out_size, void* d_ws,
                              size_t ws_size, hipStream_t stream) {
  const float* ze = (const float*)d_in[0];
  const float* cb = (const float*)d_in[1];
  float* out = (float*)d_out;

  unsigned short* Cs = (unsigned short*)d_ws;
  float* cnorm = (float*)((char*)d_ws + CNORM_OFF);
  int* qcnt = (int*)((char*)d_ws + QCNT_OFF);
  int* qtok = (int*)((char*)d_ws + QTOK_OFF);
  unsigned long long* kmin = (unsigned long long*)((char*)d_ws + KMIN_OFF);

  prep_kernel<<<KCODES / 4, 256, 0, stream>>>(cb, Cs, cnorm, qcnt);
  vq_mfma_kernel<<<M_TOK / BM, 256, 0, stream>>>(
      ze, Cs, cnorm, cb, qcnt, qtok, kmin, out, out + (size_t)M_TOK * DIM);
  rescan_part_kernel<<<4096, 256, 0, stream>>>(ze, cb, cnorm, qcnt, qtok,
                                               kmin);
  rescan_apply_kernel<<<256, 256, 0, stream>>>(cb, qcnt, qtok, kmin, out,
                                               out + (size_t)M_TOK * DIM);
}